// Round 6
// baseline (521.819 us; speedup 1.0000x reference)
//
#include <hip/hip_runtime.h>
#include <cstddef>

#define T_TOT 8192
#define M_    512
#define HS_   512
#define D_    300
#define P_    8
#define TT    16                // tokens per chunk
#define NBLK_Y 32               // persistent blocks per expert
#define KSTEP 8                 // h rows per staged W tile (16 KB)
#define NSTEP (HS_ / KSTEP)     // 64
#define CNT_STRIDE 16           // pad global counters 64B apart

__device__ __forceinline__ void gload_lds16(const float* g, float* l) {
    __builtin_amdgcn_global_load_lds(
        (const __attribute__((address_space(1))) unsigned int*)g,
        (__attribute__((address_space(3))) unsigned int*)l, 16, 0, 0);
}

// ---------------- routing / compaction (hierarchical atomics) ----------------
__global__ __launch_bounds__(256) void route_kernel(
    const int* __restrict__ inp_word, const int* __restrict__ inp_pos,
    int* __restrict__ cnt, int* __restrict__ perm,
    float* __restrict__ out_word, float* __restrict__ out_maskm,
    float* __restrict__ out_maskn)
{
    __shared__ int lcnt[P_];
    __shared__ int lbase[P_];
    int tid = threadIdx.x;
    int t = blockIdx.x * 256 + tid;
    if (tid < P_) lcnt[tid] = 0;
    __syncthreads();

    int pp = inp_pos[t];
    out_maskm[t] = (pp < P_) ? 1.0f : 0.0f;
    out_maskn[t] = (pp < 2)  ? 1.0f : 0.0f;
    int loc = 0;
    if (pp < P_) {
        loc = atomicAdd(&lcnt[pp], 1);
    } else {
        out_word[t] = (float)inp_word[t];
    }
    __syncthreads();
    if (tid < P_) lbase[tid] = atomicAdd(&cnt[tid * CNT_STRIDE], lcnt[tid]);
    __syncthreads();
    if (pp < P_) perm[pp * T_TOT + lbase[pp] + loc] = t;
}

// ---------------- base embedding copy for non-selected tokens ----------------
__global__ __launch_bounds__(128) void base_emb_kernel(
    const int* __restrict__ inp_word, const int* __restrict__ inp_pos,
    const float* __restrict__ wemb, float* __restrict__ out_emb)
{
    int t = blockIdx.x;
    if (inp_pos[t] < P_) return;
    int w = inp_word[t];
    if (threadIdx.x < 75) {          // 300 floats = 75 float4
        float4 v = *(const float4*)&wemb[(size_t)w * D_ + threadIdx.x * 4];
        *(float4*)&out_emb[(size_t)t * D_ + threadIdx.x * 4] = v;
    }
}

// -- per-expert kernel: persistent blocks, TT=16, 512 thr, dbuf W DMA (R4) ---
__global__ __launch_bounds__(512, 2) void expert_kernel(
    const float* __restrict__ ctx,   const float* __restrict__ wemb,
    const float* __restrict__ dec_W, const float* __restrict__ dec_b,
    const int*   __restrict__ tgt,   const float* __restrict__ gumbel,
    const int*   __restrict__ cnt,   const int*   __restrict__ perm,
    float* __restrict__ out_word,    float* __restrict__ out_emb)
{
    int p = blockIdx.x;                   // expert == flat%8 == XCD (L2 pin)
    int count = cnt[p * CNT_STRIDE];

    __shared__ float ctxb[TT][HS_];            // 32 KB: ctx tile -> logits -> sft
    __shared__ float wbuf[2][KSTEP][M_];       // 32 KB: double-buffered W tiles
    __shared__ int   tok_ids[TT];
    __shared__ int   tw_s[M_];

    int tn = threadIdx.x;
    tw_s[tn] = tgt[p * M_ + tn];               // 512 threads, one each

    const float* Wp = dec_W + (size_t)p * HS_ * M_;
    int tl = tn & 255;                         // m-pair index
    int half = tn >> 8;                        // token half (0: 0-7, 1: 8-15)
    int m0 = tl * 2;
    int tokbase = half * 8;
    float b0 = dec_b[p * M_ + m0];
    float b1 = dec_b[p * M_ + m0 + 1];
    int wave = tn >> 6, lane = tn & 63;

    for (int chunk = blockIdx.y; chunk * TT < count; chunk += NBLK_Y) {
        int start = chunk * TT;
        int n = min(TT, count - start);

        if (tn < TT) tok_ids[tn] = (tn < n) ? perm[p * T_TOT + start + tn] : -1;
        __syncthreads();

        // prologue: DMA W tile 0 (16 KB = 1024 float4, 2 per thread)
        gload_lds16(Wp + tn * 4,        &wbuf[0][0][0] + tn * 4);
        gload_lds16(Wp + 2048 + tn * 4, &wbuf[0][0][0] + 2048 + tn * 4);

        // stage ctx tile (16 tokens x 512 = 2048 float4s, 4 per thread)
        #pragma unroll
        for (int it = 0; it < 4; ++it) {
            int idx  = tn + it * 512;
            int tok  = idx >> 7;
            int pos4 = idx & 127;
            int t = tok_ids[tok];
            float4 v = make_float4(0.f, 0.f, 0.f, 0.f);
            if (t >= 0) v = *(const float4*)&ctx[(size_t)t * HS_ + pos4 * 4];
            *(float4*)&ctxb[tok][pos4 * 4] = v;
        }
        __syncthreads();   // drains vmcnt (tile 0 landed) + ctx stores

        // ---- phase 1: logits[16][512] = ctx @ W  (8 tokens x 2 cols/thread) -
        float accA[8], accB[8];
        #pragma unroll
        for (int k = 0; k < 8; ++k) { accA[k] = 0.f; accB[k] = 0.f; }

        int cur = 0;
        for (int step = 0; step < NSTEP; ++step) {
            if (step + 1 < NSTEP) {          // issue next tile's DMA first
                const float* src = Wp + (size_t)(step + 1) * KSTEP * M_;
                float* dst = &wbuf[cur ^ 1][0][0];
                gload_lds16(src + tn * 4,        dst + tn * 4);
                gload_lds16(src + 2048 + tn * 4, dst + 2048 + tn * 4);
            }
            #pragma unroll
            for (int h4 = 0; h4 < KSTEP / 4; ++h4) {
                float2 w0 = *(const float2*)&wbuf[cur][h4 * 4 + 0][m0];
                float2 w1 = *(const float2*)&wbuf[cur][h4 * 4 + 1][m0];
                float2 w2 = *(const float2*)&wbuf[cur][h4 * 4 + 2][m0];
                float2 w3 = *(const float2*)&wbuf[cur][h4 * 4 + 3][m0];
                #pragma unroll
                for (int k = 0; k < 8; ++k) {
                    float4 c = *(const float4*)&ctxb[tokbase + k][step * KSTEP + h4 * 4];
                    accA[k] = fmaf(c.x, w0.x, fmaf(c.y, w1.x, fmaf(c.z, w2.x, fmaf(c.w, w3.x, accA[k]))));
                    accB[k] = fmaf(c.x, w0.y, fmaf(c.y, w1.y, fmaf(c.z, w2.y, fmaf(c.w, w3.y, accB[k]))));
                }
            }
            __syncthreads();   // next tile landed; all done with wbuf[cur]
            cur ^= 1;
        }

        // logits + bias -> reuse ctxb as logits/sft buffer
        #pragma unroll
        for (int k = 0; k < 8; ++k) {
            *(float2*)&ctxb[tokbase + k][m0] = make_float2(accA[k] + b0, accB[k] + b1);
        }
        __syncthreads();

        // ---- phase 2: double softmax + gumbel argmax (1 wave per 2 tokens) --
        #pragma unroll
        for (int ti = 0; ti < 2; ++ti) {
            int tok = wave * 2 + ti;
            if (tok >= n) continue;
            int t = tok_ids[tok];
            float l[8];
            #pragma unroll
            for (int j = 0; j < 8; ++j) l[j] = ctxb[tok][j * 64 + lane];
            float mx = l[0];
            #pragma unroll
            for (int j = 1; j < 8; ++j) mx = fmaxf(mx, l[j]);
            for (int off = 32; off; off >>= 1) mx = fmaxf(mx, __shfl_xor(mx, off, 64));

            float ex[8];
            float se = 0.f;
            #pragma unroll
            for (int j = 0; j < 8; ++j) { ex[j] = expf(l[j] - mx); se += ex[j]; }
            for (int off = 32; off; off >>= 1) se += __shfl_xor(se, off, 64);

            const float* gp = gumbel + ((size_t)p * T_TOT + t) * M_;
            float s[8];
            float bm = -3.0e38f;
            int   bi = 0x7fffffff;
            #pragma unroll
            for (int j = 0; j < 8; ++j) {
                float q  = ex[j] / se;
                float sv = logf(q + 1e-12f) + gp[j * 64 + lane];
                s[j] = sv;
                if (sv > bm) { bm = sv; bi = j * 64 + lane; }   // strict > = first idx
            }
            for (int off = 32; off; off >>= 1) {
                float ov = __shfl_xor(bm, off, 64);
                int   oi = __shfl_xor(bi, off, 64);
                if (ov > bm || (ov == bm && oi < bi)) { bm = ov; bi = oi; }
            }

            float e2[8];
            float s2 = 0.f;
            #pragma unroll
            for (int j = 0; j < 8; ++j) { e2[j] = expf(s[j] - bm); s2 += e2[j]; }
            for (int off = 32; off; off >>= 1) s2 += __shfl_xor(s2, off, 64);

            #pragma unroll
            for (int j = 0; j < 8; ++j) ctxb[tok][j * 64 + lane] = e2[j] / s2;

            if (lane == 0) out_word[t] = (float)tw_s[bi];
        }
        __syncthreads();

        // ---- phase 3: emb[16][300] = sft @ target embeddings (1 d/thread) ---
        if (tn < D_) {
            int d0 = tn;
            float ac[TT];
            #pragma unroll
            for (int k = 0; k < TT; ++k) ac[k] = 0.f;

            #pragma unroll 4
            for (int m4 = 0; m4 < M_ / 4; ++m4) {
                int t0 = tw_s[m4 * 4 + 0];
                int t1 = tw_s[m4 * 4 + 1];
                int t2 = tw_s[m4 * 4 + 2];
                int t3 = tw_s[m4 * 4 + 3];
                float e0 = wemb[(size_t)t0 * D_ + d0];
                float e1 = wemb[(size_t)t1 * D_ + d0];
                float e2 = wemb[(size_t)t2 * D_ + d0];
                float e3 = wemb[(size_t)t3 * D_ + d0];
                #pragma unroll
                for (int k = 0; k < TT; ++k) {
                    float4 sv = *(const float4*)&ctxb[k][m4 * 4];  // LDS broadcast
                    ac[k] = fmaf(sv.x, e0, fmaf(sv.y, e1, fmaf(sv.z, e2, fmaf(sv.w, e3, ac[k]))));
                }
            }
            #pragma unroll
            for (int k = 0; k < TT; ++k) {
                if (k < n) {
                    int t = tok_ids[k];
                    out_emb[(size_t)t * D_ + d0] = ac[k];
                }
            }
        }
        __syncthreads();   // protect ctxb/tok_ids before next chunk restages
    }
}

// ---------------- launch ----------------
extern "C" void kernel_launch(void* const* d_in, const int* in_sizes, int n_in,
                              void* d_out, int out_size, void* d_ws, size_t ws_size,
                              hipStream_t stream)
{
    const int*   inp_word = (const int*)d_in[0];
    const int*   inp_pos  = (const int*)d_in[1];
    const float* ctx      = (const float*)d_in[2];
    const float* wemb     = (const float*)d_in[3];
    const float* dec_W    = (const float*)d_in[4];
    const float* dec_b    = (const float*)d_in[5];
    const int*   tgt      = (const int*)d_in[6];
    const float* gumbel   = (const float*)d_in[7];

    float* out       = (float*)d_out;
    float* out_word  = out;                          // [8192]
    float* out_emb   = out + T_TOT;                  // [8192][300]
    float* out_maskm = out + T_TOT + T_TOT * D_;     // [8192]
    float* out_maskn = out_maskm + T_TOT;            // [8192]

    int* cnt  = (int*)d_ws;                          // [8 * CNT_STRIDE]
    int* perm = cnt + P_ * CNT_STRIDE;               // [8][8192]

    hipMemsetAsync(d_ws, 0, P_ * CNT_STRIDE * sizeof(int), stream);
    route_kernel<<<T_TOT / 256, 256, 0, stream>>>(
        inp_word, inp_pos, cnt, perm, out_word, out_maskm, out_maskn);
    base_emb_kernel<<<T_TOT, 128, 0, stream>>>(inp_word, inp_pos, wemb, out_emb);
    // grid (8, 32): 256 persistent blocks; blockIdx.x == expert == flat%8 ==
    // XCD -> each XCD's L2 caches exactly one expert's 1 MB dec_W panel.
    expert_kernel<<<dim3(P_, NBLK_Y), 512, 0, stream>>>(
        ctx, wemb, dec_W, dec_b, tgt, gumbel, cnt, perm, out_word, out_emb);
}

// Round 9
// 425.120 us; speedup vs baseline: 1.2275x; 1.2275x over previous
//
#include <hip/hip_runtime.h>
#include <cstddef>

#define T_TOT 8192
#define M_    512
#define HS_   512
#define D_    300
#define P_    8
#define TT    8                 // tokens per block
#define CNT_STRIDE 16           // pad global counters 64B apart

// ---------------- routing / compaction (hierarchical atomics) ----------------
__global__ __launch_bounds__(256) void route_kernel(
    const int* __restrict__ inp_word, const int* __restrict__ inp_pos,
    int* __restrict__ cnt, int* __restrict__ perm,
    float* __restrict__ out_word, float* __restrict__ out_maskm,
    float* __restrict__ out_maskn)
{
    __shared__ int lcnt[P_];
    __shared__ int lbase[P_];
    int tid = threadIdx.x;
    int t = blockIdx.x * 256 + tid;
    if (tid < P_) lcnt[tid] = 0;
    __syncthreads();

    int pp = inp_pos[t];
    out_maskm[t] = (pp < P_) ? 1.0f : 0.0f;
    out_maskn[t] = (pp < 2)  ? 1.0f : 0.0f;
    int loc = 0;
    if (pp < P_) {
        loc = atomicAdd(&lcnt[pp], 1);
    } else {
        out_word[t] = (float)inp_word[t];
    }
    __syncthreads();
    if (tid < P_) lbase[tid] = atomicAdd(&cnt[tid * CNT_STRIDE], lcnt[tid]);
    __syncthreads();
    if (pp < P_) perm[pp * T_TOT + lbase[pp] + loc] = t;
}

// ---------------- base embedding copy for non-selected tokens ----------------
__global__ __launch_bounds__(128) void base_emb_kernel(
    const int* __restrict__ inp_word, const int* __restrict__ inp_pos,
    const float* __restrict__ wemb, float* __restrict__ out_emb)
{
    int t = blockIdx.x;
    if (inp_pos[t] < P_) return;
    int w = inp_word[t];
    if (threadIdx.x < 75) {          // 300 floats = 75 float4
        float4 v = *(const float4*)&wemb[(size_t)w * D_ + threadIdx.x * 4];
        *(float4*)&out_emb[(size_t)t * D_ + threadIdx.x * 4] = v;
    }
}

// --- per-expert kernel: 512 thr, 1 col/thread, W from L2, no W staging ------
__global__ __launch_bounds__(512, 4) void expert_kernel(
    const float* __restrict__ ctx,   const float* __restrict__ wemb,
    const float* __restrict__ dec_W, const float* __restrict__ dec_b,
    const int*   __restrict__ tgt,   const float* __restrict__ gumbel,
    const int*   __restrict__ cnt,   const int*   __restrict__ perm,
    float* __restrict__ out_word,    float* __restrict__ out_emb)
{
    int p = blockIdx.x;                   // expert == flat%8 == XCD (L2 pin)
    int count = cnt[p * CNT_STRIDE];
    int start = blockIdx.y * TT;
    if (start >= count) return;
    int n = min(TT, count - start);

    __shared__ float ctxb[TT][HS_];            // 16 KB: ctx tile -> logits -> sft
    __shared__ int   tok_ids[TT];
    __shared__ int   tw_s[M_];

    int tn = threadIdx.x;
    if (tn < TT) tok_ids[tn] = (tn < n) ? perm[p * T_TOT + start + tn] : -1;
    tw_s[tn & 511] = tgt[p * M_ + (tn & 511)];  // 512 threads, one each
    __syncthreads();                            // tok_ids visible

    // stage ctx tile (8 tokens x 512 = 1024 float4s, 2 per thread)
    #pragma unroll
    for (int it = 0; it < 2; ++it) {
        int idx  = tn + it * 512;
        int tok  = idx >> 7;
        int pos4 = idx & 127;
        int t = tok_ids[tok];
        float4 v = make_float4(0.f, 0.f, 0.f, 0.f);
        if (t >= 0) v = *(const float4*)&ctx[(size_t)t * HS_ + pos4 * 4];
        *(float4*)&ctxb[tok][pos4 * 4] = v;
    }
    __syncthreads();

    // ---- phase 1: logits[8][512] = ctx @ W  (1 m-col, 8 tokens per thread) --
    const float* Wp = dec_W + (size_t)p * HS_ * M_ + tn;   // column tn
    float acc[TT];
    #pragma unroll
    for (int k = 0; k < TT; ++k) acc[k] = 0.f;

    #pragma unroll 2
    for (int h4 = 0; h4 < HS_ / 4; ++h4) {
        float w0 = Wp[(size_t)(h4 * 4 + 0) * M_];
        float w1 = Wp[(size_t)(h4 * 4 + 1) * M_];
        float w2 = Wp[(size_t)(h4 * 4 + 2) * M_];
        float w3 = Wp[(size_t)(h4 * 4 + 3) * M_];
        #pragma unroll
        for (int k = 0; k < TT; ++k) {
            float4 c = *(const float4*)&ctxb[k][h4 * 4];   // wave broadcast
            acc[k] = fmaf(c.x, w0, fmaf(c.y, w1, fmaf(c.z, w2, fmaf(c.w, w3, acc[k]))));
        }
    }
    __syncthreads();   // all threads done reading ctx from LDS

    float bb = dec_b[p * M_ + tn];
    #pragma unroll
    for (int k = 0; k < TT; ++k) ctxb[k][tn] = acc[k] + bb;
    __syncthreads();

    // ---- phase 2: double softmax + gumbel argmax (one wave per token) -------
    int wave = tn >> 6, lane = tn & 63;
    int tok = wave;
    if (tok < n) {
        int t = tok_ids[tok];
        float l[8];
        #pragma unroll
        for (int j = 0; j < 8; ++j) l[j] = ctxb[tok][j * 64 + lane];
        float mx = l[0];
        #pragma unroll
        for (int j = 1; j < 8; ++j) mx = fmaxf(mx, l[j]);
        for (int off = 32; off; off >>= 1) mx = fmaxf(mx, __shfl_xor(mx, off, 64));

        float ex[8];
        float se = 0.f;
        #pragma unroll
        for (int j = 0; j < 8; ++j) { ex[j] = expf(l[j] - mx); se += ex[j]; }
        for (int off = 32; off; off >>= 1) se += __shfl_xor(se, off, 64);

        const float* gp = gumbel + ((size_t)p * T_TOT + t) * M_;
        float s[8];
        float bm = -3.0e38f;
        int   bi = 0x7fffffff;
        #pragma unroll
        for (int j = 0; j < 8; ++j) {
            float q  = ex[j] / se;
            float sv = logf(q + 1e-12f) + gp[j * 64 + lane];
            s[j] = sv;
            if (sv > bm) { bm = sv; bi = j * 64 + lane; }   // strict > = first idx
        }
        for (int off = 32; off; off >>= 1) {
            float ov = __shfl_xor(bm, off, 64);
            int   oi = __shfl_xor(bi, off, 64);
            if (ov > bm || (ov == bm && oi < bi)) { bm = ov; bi = oi; }
        }

        float e2[8];
        float s2 = 0.f;
        #pragma unroll
        for (int j = 0; j < 8; ++j) { e2[j] = expf(s[j] - bm); s2 += e2[j]; }
        for (int off = 32; off; off >>= 1) s2 += __shfl_xor(s2, off, 64);

        #pragma unroll
        for (int j = 0; j < 8; ++j) ctxb[tok][j * 64 + lane] = e2[j] / s2;

        if (lane == 0) out_word[t] = (float)tw_s[bi];
    }
    __syncthreads();

    // ---- phase 3: emb[8][300] = sft @ target embeddings (1 d-col/thread) ----
    if (tn < D_) {
        int d0 = tn;
        float ac[TT];
        #pragma unroll
        for (int k = 0; k < TT; ++k) ac[k] = 0.f;

        #pragma unroll 4
        for (int m4 = 0; m4 < M_ / 4; ++m4) {
            int t0 = tw_s[m4 * 4 + 0];
            int t1 = tw_s[m4 * 4 + 1];
            int t2 = tw_s[m4 * 4 + 2];
            int t3 = tw_s[m4 * 4 + 3];
            float e0 = wemb[(size_t)t0 * D_ + d0];
            float e1 = wemb[(size_t)t1 * D_ + d0];
            float e2 = wemb[(size_t)t2 * D_ + d0];
            float e3 = wemb[(size_t)t3 * D_ + d0];
            #pragma unroll
            for (int k = 0; k < TT; ++k) {
                float4 sv = *(const float4*)&ctxb[k][m4 * 4];  // wave broadcast
                ac[k] = fmaf(sv.x, e0, fmaf(sv.y, e1, fmaf(sv.z, e2, fmaf(sv.w, e3, ac[k]))));
            }
        }
        #pragma unroll
        for (int k = 0; k < TT; ++k) {
            if (k < n) {
                int t = tok_ids[k];
                out_emb[(size_t)t * D_ + d0] = ac[k];
            }
        }
    }
}

// ---------------- launch ----------------
extern "C" void kernel_launch(void* const* d_in, const int* in_sizes, int n_in,
                              void* d_out, int out_size, void* d_ws, size_t ws_size,
                              hipStream_t stream)
{
    const int*   inp_word = (const int*)d_in[0];
    const int*   inp_pos  = (const int*)d_in[1];
    const float* ctx      = (const float*)d_in[2];
    const float* wemb     = (const float*)d_in[3];
    const float* dec_W    = (const float*)d_in[4];
    const float* dec_b    = (const float*)d_in[5];
    const int*   tgt      = (const int*)d_in[6];
    const float* gumbel   = (const float*)d_in[7];

    float* out       = (float*)d_out;
    float* out_word  = out;                          // [8192]
    float* out_emb   = out + T_TOT;                  // [8192][300]
    float* out_maskm = out + T_TOT + T_TOT * D_;     // [8192]
    float* out_maskn = out_maskm + T_TOT;            // [8192]

    int* cnt  = (int*)d_ws;                          // [8 * CNT_STRIDE]
    int* perm = cnt + P_ * CNT_STRIDE;               // [8][8192]

    hipMemsetAsync(d_ws, 0, P_ * CNT_STRIDE * sizeof(int), stream);
    route_kernel<<<T_TOT / 256, 256, 0, stream>>>(
        inp_word, inp_pos, cnt, perm, out_word, out_maskm, out_maskn);
    base_emb_kernel<<<T_TOT, 128, 0, stream>>>(inp_word, inp_pos, wemb, out_emb);
    // grid (8, 1024): blockIdx.x == expert == flat%8 == XCD -> each XCD's L2
    // caches exactly one expert's 1 MB dec_W panel; worst-case counts covered.
    expert_kernel<<<dim3(P_, T_TOT / TT), 512, 0, stream>>>(
        ctx, wemb, dec_W, dec_b, tgt, gumbel, cnt, perm, out_word, out_emb);
}